// Round 2
// baseline (583.886 us; speedup 1.0000x reference)
//
#include <hip/hip_runtime.h>
#include <math.h>

// Problem constants (fixed by the reference)
constexpr int Bn = 16;    // batch
constexpr int Cn = 256;   // in channels
constexpr int Mn = 128;   // med channels
constexpr int Nn = 4096;  // H*W

// ---------------------------------------------------------------------------
// K1: o = w_o @ x + b_o ; v = w_v @ x + b_v   (per batch [M,C]x[C,N])
// block: 256 thr, tile m=128 (all) x n=32, K-chunks of 32. Shares x tile for
// both outputs. micro-tile 4m x 4n per array per thread.
// ---------------------------------------------------------------------------
__global__ __launch_bounds__(256) void k_proj(
    const float* __restrict__ x,
    const float* __restrict__ w_o, const float* __restrict__ b_o,
    const float* __restrict__ w_v, const float* __restrict__ b_v,
    float* __restrict__ o, float* __restrict__ v) {
  __shared__ float xs[32][32];       // [k][n]
  __shared__ float wos[32][132];     // [k][m] padded (132*4B=528=16B aligned rows)
  __shared__ float wvs[32][132];
  const int b = blockIdx.y;
  const int n_t = blockIdx.x * 32;
  const int t = threadIdx.x;
  const int m0 = (t >> 3) * 4;       // 0..124
  const int n0 = (t & 7) * 4;        // 0..28
  float acc_o[4][4] = {};
  float acc_v[4][4] = {};
  const float* xb = x + (size_t)b * Cn * Nn;

  for (int k0 = 0; k0 < Cn; k0 += 32) {
    { // x tile: 32k x 32n
      int kr = t >> 3;               // 0..31
      int nc = (t & 7) * 4;
      *(float4*)&xs[kr][nc] = *(const float4*)&xb[(size_t)(k0 + kr) * Nn + n_t + nc];
    }
    { // w tiles: 128m x 32k -> transposed [k][m]
      int k4 = (t & 7) * 4;
      int mr = t >> 3;               // 0..31
#pragma unroll
      for (int p = 0; p < 4; ++p) {
        int m = mr + p * 32;
        float4 a = *(const float4*)&w_o[(size_t)m * Cn + k0 + k4];
        float4 c = *(const float4*)&w_v[(size_t)m * Cn + k0 + k4];
        wos[k4 + 0][m] = a.x; wos[k4 + 1][m] = a.y; wos[k4 + 2][m] = a.z; wos[k4 + 3][m] = a.w;
        wvs[k4 + 0][m] = c.x; wvs[k4 + 1][m] = c.y; wvs[k4 + 2][m] = c.z; wvs[k4 + 3][m] = c.w;
      }
    }
    __syncthreads();
#pragma unroll
    for (int kk = 0; kk < 32; ++kk) {
      float4 a4 = *(const float4*)&wos[kk][m0];
      float4 c4 = *(const float4*)&wvs[kk][m0];
      float4 x4 = *(const float4*)&xs[kk][n0];
      float wa[4] = {a4.x, a4.y, a4.z, a4.w};
      float wc[4] = {c4.x, c4.y, c4.z, c4.w};
      float xx[4] = {x4.x, x4.y, x4.z, x4.w};
#pragma unroll
      for (int i = 0; i < 4; ++i)
#pragma unroll
        for (int j = 0; j < 4; ++j) {
          acc_o[i][j] = fmaf(wa[i], xx[j], acc_o[i][j]);
          acc_v[i][j] = fmaf(wc[i], xx[j], acc_v[i][j]);
        }
    }
    __syncthreads();
  }
#pragma unroll
  for (int i = 0; i < 4; ++i) {
    int m = m0 + i;
    float bo = b_o[m], bv = b_v[m];
    size_t base = ((size_t)(b * Mn + m)) * Nn + n_t + n0;
    float4 ov = {acc_o[i][0] + bo, acc_o[i][1] + bo, acc_o[i][2] + bo, acc_o[i][3] + bo};
    float4 vv = {acc_v[i][0] + bv, acc_v[i][1] + bv, acc_v[i][2] + bv, acc_v[i][3] + bv};
    *(float4*)&o[base] = ov;
    *(float4*)&v[base] = vv;
  }
}

// ---------------------------------------------------------------------------
// K2: row softmax stats over N for each (b,m): rm = max, rs = sum exp(v-rm)
// ---------------------------------------------------------------------------
__global__ __launch_bounds__(256) void k_rowstats(
    const float* __restrict__ v, float* __restrict__ rm, float* __restrict__ rs) {
  const int row = blockIdx.x;  // b*M + m
  const float* vr = v + (size_t)row * Nn;
  const int t = threadIdx.x;
  float vals[16];
  float mx = -1e30f;
#pragma unroll
  for (int p = 0; p < 4; ++p) {
    float4 v4 = *(const float4*)&vr[p * 1024 + t * 4];
    vals[p * 4 + 0] = v4.x; vals[p * 4 + 1] = v4.y;
    vals[p * 4 + 2] = v4.z; vals[p * 4 + 3] = v4.w;
    mx = fmaxf(mx, fmaxf(fmaxf(v4.x, v4.y), fmaxf(v4.z, v4.w)));
  }
  __shared__ float red[256];
  red[t] = mx;
  __syncthreads();
  for (int s = 128; s > 0; s >>= 1) {
    if (t < s) red[t] = fmaxf(red[t], red[t + s]);
    __syncthreads();
  }
  mx = red[0];
  __syncthreads();
  float sum = 0.f;
#pragma unroll
  for (int i = 0; i < 16; ++i) sum += __expf(vals[i] - mx);
  red[t] = sum;
  __syncthreads();
  for (int s = 128; s > 0; s >>= 1) {
    if (t < s) red[t] += red[t + s];
    __syncthreads();
  }
  if (t == 0) { rm[row] = mx; rs[row] = red[0]; }
}

// ---------------------------------------------------------------------------
// K3: column softmax stats over M for each (b,n): cm, cs
// one thread per (b,n); column reads are coalesced across lanes (n fastest).
// ---------------------------------------------------------------------------
__global__ __launch_bounds__(256) void k_colstats(
    const float* __restrict__ v, float* __restrict__ cm, float* __restrict__ cs) {
  int idx = blockIdx.x * 256 + threadIdx.x;  // 0..B*N-1
  int b = idx >> 12;
  int n = idx & (Nn - 1);
  const float* vc = v + (size_t)b * Mn * Nn + n;
  float mx = -1e30f;
#pragma unroll 4
  for (int k = 0; k < Mn; ++k) mx = fmaxf(mx, vc[(size_t)k * Nn]);
  float sum = 0.f;
#pragma unroll 4
  for (int k = 0; k < Mn; ++k) sum += __expf(vc[(size_t)k * Nn] - mx);
  cm[idx] = mx;
  cs[idx] = sum;
}

// ---------------------------------------------------------------------------
// K4 (v2): A[b,m,k] += sum_n ev[m,n] * es[k,n]
//   ev[m,n] = exp(v[m,n]-rm[m])/rs[m]   (row softmax of v)
//   es[k,n] = exp(v[k,n]-cm[n])/cs[n]   (col softmax of v)
// One block = FULL 128x128 A tile over a 128-column n-slice. v is read ONCE
// per slice and exp'd in-register for both operands. Grid: 32 slices x 16 b
// = 512 blocks (2/CU). Micro-tile 8x8 (64 acc VGPRs, 16 FMA per ds_read_b128).
// Epilogue: atomicAdd into pre-zeroed A (1 MB, L2-resident).
// ---------------------------------------------------------------------------
__global__ __launch_bounds__(256) void k_accA(
    const float* __restrict__ v,
    const float* __restrict__ rm, const float* __restrict__ rs,
    const float* __restrict__ cm, const float* __restrict__ cs,
    float* __restrict__ A) {
  __shared__ float vE[32][132];  // [n-in-chunk][m]  ev operand
  __shared__ float vS[32][132];  // [n-in-chunk][k]  es operand
  const int b = blockIdx.y;
  const int nbase = blockIdx.x * 128;
  const int t = threadIdx.x;
  const int m0 = (t >> 4) * 8;   // 0..120
  const int k0 = (t & 15) * 8;   // 0..120
  // staging coords: rows rbase+32p (p=0..3), cols c4..c4+3 within 32-chunk
  const int rbase = t >> 3;      // 0..31
  const int c4 = (t & 7) * 4;    // 0..28
  float acc[8][8] = {};
  const float* vb = v + (size_t)b * Mn * Nn;

  float rmv[4], irs[4];
#pragma unroll
  for (int p = 0; p < 4; ++p) {
    int r = rbase + 32 * p;
    rmv[p] = rm[b * Mn + r];
    irs[p] = 1.0f / rs[b * Mn + r];
  }

  for (int ch = 0; ch < 128; ch += 32) {
    const int n0c = nbase + ch;
    float4 cm4 = *(const float4*)&cm[b * Nn + n0c + c4];
    float4 cs4 = *(const float4*)&cs[b * Nn + n0c + c4];
    float cmv[4] = {cm4.x, cm4.y, cm4.z, cm4.w};
    float icv[4] = {1.0f / cs4.x, 1.0f / cs4.y, 1.0f / cs4.z, 1.0f / cs4.w};
#pragma unroll
    for (int p = 0; p < 4; ++p) {
      int r = rbase + 32 * p;
      float4 vv = *(const float4*)&vb[(size_t)r * Nn + n0c + c4];
      float a[4] = {vv.x, vv.y, vv.z, vv.w};
#pragma unroll
      for (int q = 0; q < 4; ++q) {
        vE[c4 + q][r] = __expf(a[q] - rmv[p]) * irs[p];
        vS[c4 + q][r] = __expf(a[q] - cmv[q]) * icv[q];
      }
    }
    __syncthreads();
#pragma unroll
    for (int jj = 0; jj < 32; ++jj) {
      float4 e0 = *(const float4*)&vE[jj][m0];
      float4 e1 = *(const float4*)&vE[jj][m0 + 4];
      float4 s0 = *(const float4*)&vS[jj][k0];
      float4 s1 = *(const float4*)&vS[jj][k0 + 4];
      float e[8] = {e0.x, e0.y, e0.z, e0.w, e1.x, e1.y, e1.z, e1.w};
      float s[8] = {s0.x, s0.y, s0.z, s0.w, s1.x, s1.y, s1.z, s1.w};
#pragma unroll
      for (int i = 0; i < 8; ++i)
#pragma unroll
        for (int j = 0; j < 8; ++j) acc[i][j] = fmaf(e[i], s[j], acc[i][j]);
    }
    __syncthreads();
  }
#pragma unroll
  for (int i = 0; i < 8; ++i)
#pragma unroll
    for (int j = 0; j < 8; ++j)
      atomicAdd(&A[((size_t)(b * Mn + m0 + i)) * Mn + k0 + j], acc[i][j]);
}

// ---------------------------------------------------------------------------
// K5: W2[b,c,m] = sum_k w_c[c,k] * A[b,m,k]   ([256x128]x[128x128]^T per b)
// grid: (m-tile 2, c-tile 4, B), tile 64x64, K=128 in two 64-chunks via LDS.
// ---------------------------------------------------------------------------
__global__ __launch_bounds__(256) void k_w2(
    const float* __restrict__ w_c, const float* __restrict__ A, float* __restrict__ W2) {
  __shared__ float As[64][68];   // [k][m-local]
  __shared__ float wcs[64][68];  // [k][c-local]
  const int b = blockIdx.z;
  const int m0 = blockIdx.x * 64;
  const int c0 = blockIdx.y * 64;
  const int t = threadIdx.x;
  const int tc = (t >> 4) * 4, tmm = (t & 15) * 4;
  float acc[4][4] = {};
  for (int k0 = 0; k0 < Mn; k0 += 64) {
    int r = t >> 2;             // 0..63
    int k4 = (t & 3) * 4;
#pragma unroll
    for (int p = 0; p < 4; ++p) {
      int k = k4 + p * 16;
      float4 a4 = *(const float4*)&A[((size_t)(b * Mn + m0 + r)) * Mn + k0 + k];
      As[k + 0][r] = a4.x; As[k + 1][r] = a4.y; As[k + 2][r] = a4.z; As[k + 3][r] = a4.w;
      float4 w4 = *(const float4*)&w_c[(size_t)(c0 + r) * Mn + k0 + k];
      wcs[k + 0][r] = w4.x; wcs[k + 1][r] = w4.y; wcs[k + 2][r] = w4.z; wcs[k + 3][r] = w4.w;
    }
    __syncthreads();
#pragma unroll
    for (int kk = 0; kk < 64; ++kk) {
      float4 w4 = *(const float4*)&wcs[kk][tc];
      float4 a4 = *(const float4*)&As[kk][tmm];
      float w[4] = {w4.x, w4.y, w4.z, w4.w};
      float a[4] = {a4.x, a4.y, a4.z, a4.w};
#pragma unroll
      for (int i = 0; i < 4; ++i)
#pragma unroll
        for (int jj = 0; jj < 4; ++jj) acc[i][jj] = fmaf(w[i], a[jj], acc[i][jj]);
    }
    __syncthreads();
  }
#pragma unroll
  for (int i = 0; i < 4; ++i) {
    size_t base = ((size_t)(b * Cn + c0 + tc + i)) * Mn + m0 + tmm;
    float4 r4 = {acc[i][0], acc[i][1], acc[i][2], acc[i][3]};
    *(float4*)&W2[base] = r4;
  }
}

// ---------------------------------------------------------------------------
// K6: out[b,c,n] = gamma*relu(sum_m W2[b,c,m]*o[b,m,n] + b_c[c]) + x[b,c,n]
// grid: (n-tile 32, c-tile 4, B); tile 64c x 128n, K=128 in 32-chunks.
// micro: 4c x (4n + 4n at +64) per thread.
// ---------------------------------------------------------------------------
__global__ __launch_bounds__(256) void k_final(
    const float* __restrict__ W2, const float* __restrict__ o,
    const float* __restrict__ x, const float* __restrict__ b_c,
    const float* __restrict__ gamma, float* __restrict__ out) {
  __shared__ float os[32][128];  // [k][n]
  __shared__ float w2T[32][68];  // [k][c-local]
  const int b = blockIdx.z;
  const int c_t = blockIdx.y * 64;
  const int n_t = blockIdx.x * 128;
  const int t = threadIdx.x;
  const int tc = (t >> 4) * 4;       // 0..60
  const int tn = (t & 15) * 4;       // 0..60 (+64 for second half)
  float acc[4][8] = {};
  const float* ob = o + (size_t)b * Mn * Nn;
  const float* W2b = W2 + ((size_t)b * Cn + c_t) * Mn;

  for (int k0 = 0; k0 < Mn; k0 += 32) {
    { // o tile 32k x 128n
      int kr = t >> 5, nc = (t & 31) * 4;
#pragma unroll
      for (int p = 0; p < 4; ++p)
        *(float4*)&os[kr + p * 8][nc] =
            *(const float4*)&ob[(size_t)(k0 + kr + p * 8) * Nn + n_t + nc];
    }
    { // W2 tile 64c x 32k -> [k][c]
      int cc = t >> 2, k4 = (t & 3) * 4;
#pragma unroll
      for (int p = 0; p < 2; ++p) {
        int k = k4 + p * 16;
        float4 w4 = *(const float4*)&W2b[(size_t)cc * Mn + k0 + k];
        w2T[k + 0][cc] = w4.x; w2T[k + 1][cc] = w4.y;
        w2T[k + 2][cc] = w4.z; w2T[k + 3][cc] = w4.w;
      }
    }
    __syncthreads();
#pragma unroll
    for (int kk = 0; kk < 32; ++kk) {
      float4 w4 = *(const float4*)&w2T[kk][tc];
      float4 oa = *(const float4*)&os[kk][tn];
      float4 obb = *(const float4*)&os[kk][tn + 64];
      float w[4] = {w4.x, w4.y, w4.z, w4.w};
      float oo[8] = {oa.x, oa.y, oa.z, oa.w, obb.x, obb.y, obb.z, obb.w};
#pragma unroll
      for (int i = 0; i < 4; ++i)
#pragma unroll
        for (int jj = 0; jj < 8; ++jj) acc[i][jj] = fmaf(w[i], oo[jj], acc[i][jj]);
    }
    __syncthreads();
  }
  float g = gamma[0];
#pragma unroll
  for (int i = 0; i < 4; ++i) {
    int c = c_t + tc + i;
    float bias = b_c[c];
    size_t base = ((size_t)(b * Cn + c)) * Nn + n_t + tn;
#pragma unroll
    for (int h = 0; h < 2; ++h) {
      size_t idx = base + h * 64;
      float4 x4 = *(const float4*)&x[idx];
      float4 r;
      r.x = g * fmaxf(acc[i][h * 4 + 0] + bias, 0.f) + x4.x;
      r.y = g * fmaxf(acc[i][h * 4 + 1] + bias, 0.f) + x4.y;
      r.z = g * fmaxf(acc[i][h * 4 + 2] + bias, 0.f) + x4.z;
      r.w = g * fmaxf(acc[i][h * 4 + 3] + bias, 0.f) + x4.w;
      *(float4*)&out[idx] = r;
    }
  }
}

// ---------------------------------------------------------------------------
extern "C" void kernel_launch(void* const* d_in, const int* in_sizes, int n_in,
                              void* d_out, int out_size, void* d_ws, size_t ws_size,
                              hipStream_t stream) {
  const float* x   = (const float*)d_in[0];
  const float* w_o = (const float*)d_in[1];
  const float* b_o = (const float*)d_in[2];
  const float* w_v = (const float*)d_in[3];
  const float* b_v = (const float*)d_in[4];
  const float* w_c = (const float*)d_in[5];
  const float* b_c = (const float*)d_in[6];
  const float* gm  = (const float*)d_in[7];

  float* ws = (float*)d_ws;
  float* o  = ws;                               // B*M*N
  float* v  = o  + (size_t)Bn * Mn * Nn;        // B*M*N
  float* rm = v  + (size_t)Bn * Mn * Nn;        // B*M
  float* rs = rm + Bn * Mn;                     // B*M
  float* cm = rs + Bn * Mn;                     // B*N
  float* cs = cm + Bn * Nn;                     // B*N
  float* A  = cs + Bn * Nn;                     // B*M*M
  float* W2 = A  + (size_t)Bn * Mn * Mn;        // B*C*M

  k_proj<<<dim3(Nn / 32, Bn), 256, 0, stream>>>(x, w_o, b_o, w_v, b_v, o, v);
  k_rowstats<<<dim3(Bn * Mn), 256, 0, stream>>>(v, rm, rs);
  k_colstats<<<dim3(Bn * Nn / 256), 256, 0, stream>>>(v, cm, cs);
  hipMemsetAsync(A, 0, (size_t)Bn * Mn * Mn * sizeof(float), stream);
  k_accA<<<dim3(32, Bn), 256, 0, stream>>>(v, rm, rs, cm, cs, A);
  k_w2<<<dim3(Mn / 64, Cn / 64, Bn), 256, 0, stream>>>(w_c, A, W2);
  k_final<<<dim3(Nn / 128, Cn / 64, Bn), 256, 0, stream>>>(W2, o, x, b_c, gm, (float*)d_out);
}

// Round 3
// 374.695 us; speedup vs baseline: 1.5583x; 1.5583x over previous
//
#include <hip/hip_runtime.h>
#include <math.h>

// Problem constants (fixed by the reference)
constexpr int Bn = 16;    // batch
constexpr int Cn = 256;   // in channels
constexpr int Mn = 128;   // med channels
constexpr int Nn = 4096;  // H*W

// ---------------------------------------------------------------------------
// K1: o = w_o @ x + b_o ; v = w_v @ x + b_v   (per batch [M,C]x[C,N])
// block: 256 thr, tile m=128 (all) x n=32, K-chunks of 32. Shares x tile for
// both outputs. micro-tile 4m x 4n per array per thread.
// ---------------------------------------------------------------------------
__global__ __launch_bounds__(256) void k_proj(
    const float* __restrict__ x,
    const float* __restrict__ w_o, const float* __restrict__ b_o,
    const float* __restrict__ w_v, const float* __restrict__ b_v,
    float* __restrict__ o, float* __restrict__ v) {
  __shared__ float xs[32][32];       // [k][n]
  __shared__ float wos[32][132];     // [k][m] padded
  __shared__ float wvs[32][132];
  const int b = blockIdx.y;
  const int n_t = blockIdx.x * 32;
  const int t = threadIdx.x;
  const int m0 = (t >> 3) * 4;       // 0..124
  const int n0 = (t & 7) * 4;        // 0..28
  float acc_o[4][4] = {};
  float acc_v[4][4] = {};
  const float* xb = x + (size_t)b * Cn * Nn;

  for (int k0 = 0; k0 < Cn; k0 += 32) {
    { // x tile: 32k x 32n
      int kr = t >> 3;               // 0..31
      int nc = (t & 7) * 4;
      *(float4*)&xs[kr][nc] = *(const float4*)&xb[(size_t)(k0 + kr) * Nn + n_t + nc];
    }
    { // w tiles: 128m x 32k -> transposed [k][m]
      int k4 = (t & 7) * 4;
      int mr = t >> 3;               // 0..31
#pragma unroll
      for (int p = 0; p < 4; ++p) {
        int m = mr + p * 32;
        float4 a = *(const float4*)&w_o[(size_t)m * Cn + k0 + k4];
        float4 c = *(const float4*)&w_v[(size_t)m * Cn + k0 + k4];
        wos[k4 + 0][m] = a.x; wos[k4 + 1][m] = a.y; wos[k4 + 2][m] = a.z; wos[k4 + 3][m] = a.w;
        wvs[k4 + 0][m] = c.x; wvs[k4 + 1][m] = c.y; wvs[k4 + 2][m] = c.z; wvs[k4 + 3][m] = c.w;
      }
    }
    __syncthreads();
#pragma unroll
    for (int kk = 0; kk < 32; ++kk) {
      float4 a4 = *(const float4*)&wos[kk][m0];
      float4 c4 = *(const float4*)&wvs[kk][m0];
      float4 x4 = *(const float4*)&xs[kk][n0];
      float wa[4] = {a4.x, a4.y, a4.z, a4.w};
      float wc[4] = {c4.x, c4.y, c4.z, c4.w};
      float xx[4] = {x4.x, x4.y, x4.z, x4.w};
#pragma unroll
      for (int i = 0; i < 4; ++i)
#pragma unroll
        for (int j = 0; j < 4; ++j) {
          acc_o[i][j] = fmaf(wa[i], xx[j], acc_o[i][j]);
          acc_v[i][j] = fmaf(wc[i], xx[j], acc_v[i][j]);
        }
    }
    __syncthreads();
  }
#pragma unroll
  for (int i = 0; i < 4; ++i) {
    int m = m0 + i;
    float bo = b_o[m], bv = b_v[m];
    size_t base = ((size_t)(b * Mn + m)) * Nn + n_t + n0;
    float4 ov = {acc_o[i][0] + bo, acc_o[i][1] + bo, acc_o[i][2] + bo, acc_o[i][3] + bo};
    float4 vv = {acc_v[i][0] + bv, acc_v[i][1] + bv, acc_v[i][2] + bv, acc_v[i][3] + bv};
    *(float4*)&o[base] = ov;
    *(float4*)&v[base] = vv;
  }
}

// ---------------------------------------------------------------------------
// K2: row softmax stats over N for each (b,m): rm = max, rs = sum exp(v-rm)
// ---------------------------------------------------------------------------
__global__ __launch_bounds__(256) void k_rowstats(
    const float* __restrict__ v, float* __restrict__ rm, float* __restrict__ rs) {
  const int row = blockIdx.x;  // b*M + m
  const float* vr = v + (size_t)row * Nn;
  const int t = threadIdx.x;
  float vals[16];
  float mx = -1e30f;
#pragma unroll
  for (int p = 0; p < 4; ++p) {
    float4 v4 = *(const float4*)&vr[p * 1024 + t * 4];
    vals[p * 4 + 0] = v4.x; vals[p * 4 + 1] = v4.y;
    vals[p * 4 + 2] = v4.z; vals[p * 4 + 3] = v4.w;
    mx = fmaxf(mx, fmaxf(fmaxf(v4.x, v4.y), fmaxf(v4.z, v4.w)));
  }
  __shared__ float red[256];
  red[t] = mx;
  __syncthreads();
  for (int s = 128; s > 0; s >>= 1) {
    if (t < s) red[t] = fmaxf(red[t], red[t + s]);
    __syncthreads();
  }
  mx = red[0];
  __syncthreads();
  float sum = 0.f;
#pragma unroll
  for (int i = 0; i < 16; ++i) sum += __expf(vals[i] - mx);
  red[t] = sum;
  __syncthreads();
  for (int s = 128; s > 0; s >>= 1) {
    if (t < s) red[t] += red[t + s];
    __syncthreads();
  }
  if (t == 0) { rm[row] = mx; rs[row] = red[0]; }
}

// ---------------------------------------------------------------------------
// K3: column softmax stats over M for each (b,n): cm, cs
// ---------------------------------------------------------------------------
__global__ __launch_bounds__(256) void k_colstats(
    const float* __restrict__ v, float* __restrict__ cm, float* __restrict__ cs) {
  int idx = blockIdx.x * 256 + threadIdx.x;  // 0..B*N-1
  int b = idx >> 12;
  int n = idx & (Nn - 1);
  const float* vc = v + (size_t)b * Mn * Nn + n;
  float mx = -1e30f;
#pragma unroll 4
  for (int k = 0; k < Mn; ++k) mx = fmaxf(mx, vc[(size_t)k * Nn]);
  float sum = 0.f;
#pragma unroll 4
  for (int k = 0; k < Mn; ++k) sum += __expf(vc[(size_t)k * Nn] - mx);
  cm[idx] = mx;
  cs[idx] = sum;
}

// ---------------------------------------------------------------------------
// K4 (v3): partial A per n-slice. One block = full 128x128 tile over `ncols`
// columns; v read once, exp'd in-register for both operands. NO atomics:
// each block stores its private fp32 partial tile (plain float4 stores);
// k_reduceA sums the S partials. Micro-tile 8x8.
// ---------------------------------------------------------------------------
__global__ __launch_bounds__(256) void k_accA(
    const float* __restrict__ v,
    const float* __restrict__ rm, const float* __restrict__ rs,
    const float* __restrict__ cm, const float* __restrict__ cs,
    float* __restrict__ Ap, int ncols) {
  __shared__ float vE[32][132];  // [n-in-chunk][m]  ev operand
  __shared__ float vS[32][132];  // [n-in-chunk][k]  es operand
  const int b = blockIdx.y;
  const int slice = blockIdx.x;
  const int nbase = slice * ncols;
  const int t = threadIdx.x;
  const int m0 = (t >> 4) * 8;   // 0..120
  const int k0 = (t & 15) * 8;   // 0..120
  const int rbase = t >> 3;      // 0..31
  const int c4 = (t & 7) * 4;    // 0..28
  float acc[8][8] = {};
  const float* vb = v + (size_t)b * Mn * Nn;

  float rmv[4], irs[4];
#pragma unroll
  for (int p = 0; p < 4; ++p) {
    int r = rbase + 32 * p;
    rmv[p] = rm[b * Mn + r];
    irs[p] = 1.0f / rs[b * Mn + r];
  }

  for (int ch = 0; ch < ncols; ch += 32) {
    const int n0c = nbase + ch;
    float4 cm4 = *(const float4*)&cm[b * Nn + n0c + c4];
    float4 cs4 = *(const float4*)&cs[b * Nn + n0c + c4];
    float cmv[4] = {cm4.x, cm4.y, cm4.z, cm4.w};
    float icv[4] = {1.0f / cs4.x, 1.0f / cs4.y, 1.0f / cs4.z, 1.0f / cs4.w};
#pragma unroll
    for (int p = 0; p < 4; ++p) {
      int r = rbase + 32 * p;
      float4 vv = *(const float4*)&vb[(size_t)r * Nn + n0c + c4];
      float a[4] = {vv.x, vv.y, vv.z, vv.w};
#pragma unroll
      for (int q = 0; q < 4; ++q) {
        vE[c4 + q][r] = __expf(a[q] - rmv[p]) * irs[p];
        vS[c4 + q][r] = __expf(a[q] - cmv[q]) * icv[q];
      }
    }
    __syncthreads();
#pragma unroll
    for (int jj = 0; jj < 32; ++jj) {
      float4 e0 = *(const float4*)&vE[jj][m0];
      float4 e1 = *(const float4*)&vE[jj][m0 + 4];
      float4 s0 = *(const float4*)&vS[jj][k0];
      float4 s1 = *(const float4*)&vS[jj][k0 + 4];
      float e[8] = {e0.x, e0.y, e0.z, e0.w, e1.x, e1.y, e1.z, e1.w};
      float s[8] = {s0.x, s0.y, s0.z, s0.w, s1.x, s1.y, s1.z, s1.w};
#pragma unroll
      for (int i = 0; i < 8; ++i)
#pragma unroll
        for (int j = 0; j < 8; ++j) acc[i][j] = fmaf(e[i], s[j], acc[i][j]);
    }
    __syncthreads();
  }
  // plain stores into this block's private partial tile
  float* Apb = Ap + ((size_t)slice * Bn + b) * (Mn * Mn);
#pragma unroll
  for (int i = 0; i < 8; ++i) {
#pragma unroll
    for (int j = 0; j < 8; j += 4) {
      float4 r4 = {acc[i][j], acc[i][j + 1], acc[i][j + 2], acc[i][j + 3]};
      *(float4*)&Apb[(size_t)(m0 + i) * Mn + k0 + j] = r4;
    }
  }
}

// ---------------------------------------------------------------------------
// K4b: A[b][idx] = sum_s Ap[s][b][idx] (float4 per thread, coalesced)
// ---------------------------------------------------------------------------
__global__ __launch_bounds__(256) void k_reduceA(
    const float* __restrict__ Ap, float* __restrict__ A, int S) {
  int tid = blockIdx.x * 256 + threadIdx.x;           // over Bn*Mn*Mn/4
  int idx4 = tid * 4;
  int b = idx4 / (Mn * Mn);
  int off = idx4 - b * (Mn * Mn);
  float4 s = {0.f, 0.f, 0.f, 0.f};
  for (int s0 = 0; s0 < S; ++s0) {
    float4 p = *(const float4*)&Ap[((size_t)s0 * Bn + b) * (Mn * Mn) + off];
    s.x += p.x; s.y += p.y; s.z += p.z; s.w += p.w;
  }
  *(float4*)&A[idx4] = s;
}

// ---------------------------------------------------------------------------
// K5: W2[b,c,m] = sum_k w_c[c,k] * A[b,m,k]
// ---------------------------------------------------------------------------
__global__ __launch_bounds__(256) void k_w2(
    const float* __restrict__ w_c, const float* __restrict__ A, float* __restrict__ W2) {
  __shared__ float As[64][68];   // [k][m-local]
  __shared__ float wcs[64][68];  // [k][c-local]
  const int b = blockIdx.z;
  const int m0 = blockIdx.x * 64;
  const int c0 = blockIdx.y * 64;
  const int t = threadIdx.x;
  const int tc = (t >> 4) * 4, tmm = (t & 15) * 4;
  float acc[4][4] = {};
  for (int k0 = 0; k0 < Mn; k0 += 64) {
    int r = t >> 2;             // 0..63
    int k4 = (t & 3) * 4;
#pragma unroll
    for (int p = 0; p < 4; ++p) {
      int k = k4 + p * 16;
      float4 a4 = *(const float4*)&A[((size_t)(b * Mn + m0 + r)) * Mn + k0 + k];
      As[k + 0][r] = a4.x; As[k + 1][r] = a4.y; As[k + 2][r] = a4.z; As[k + 3][r] = a4.w;
      float4 w4 = *(const float4*)&w_c[(size_t)(c0 + r) * Mn + k0 + k];
      wcs[k + 0][r] = w4.x; wcs[k + 1][r] = w4.y; wcs[k + 2][r] = w4.z; wcs[k + 3][r] = w4.w;
    }
    __syncthreads();
#pragma unroll
    for (int kk = 0; kk < 64; ++kk) {
      float4 w4 = *(const float4*)&wcs[kk][tc];
      float4 a4 = *(const float4*)&As[kk][tmm];
      float w[4] = {w4.x, w4.y, w4.z, w4.w};
      float a[4] = {a4.x, a4.y, a4.z, a4.w};
#pragma unroll
      for (int i = 0; i < 4; ++i)
#pragma unroll
        for (int jj = 0; jj < 4; ++jj) acc[i][jj] = fmaf(w[i], a[jj], acc[i][jj]);
    }
    __syncthreads();
  }
#pragma unroll
  for (int i = 0; i < 4; ++i) {
    size_t base = ((size_t)(b * Cn + c0 + tc + i)) * Mn + m0 + tmm;
    float4 r4 = {acc[i][0], acc[i][1], acc[i][2], acc[i][3]};
    *(float4*)&W2[base] = r4;
  }
}

// ---------------------------------------------------------------------------
// K6: out[b,c,n] = gamma*relu(sum_m W2[b,c,m]*o[b,m,n] + b_c[c]) + x[b,c,n]
// ---------------------------------------------------------------------------
__global__ __launch_bounds__(256) void k_final(
    const float* __restrict__ W2, const float* __restrict__ o,
    const float* __restrict__ x, const float* __restrict__ b_c,
    const float* __restrict__ gamma, float* __restrict__ out) {
  __shared__ float os[32][128];  // [k][n]
  __shared__ float w2T[32][68];  // [k][c-local]
  const int b = blockIdx.z;
  const int c_t = blockIdx.y * 64;
  const int n_t = blockIdx.x * 128;
  const int t = threadIdx.x;
  const int tc = (t >> 4) * 4;       // 0..60
  const int tn = (t & 15) * 4;       // 0..60 (+64 for second half)
  float acc[4][8] = {};
  const float* ob = o + (size_t)b * Mn * Nn;
  const float* W2b = W2 + ((size_t)b * Cn + c_t) * Mn;

  for (int k0 = 0; k0 < Mn; k0 += 32) {
    { // o tile 32k x 128n
      int kr = t >> 5, nc = (t & 31) * 4;
#pragma unroll
      for (int p = 0; p < 4; ++p)
        *(float4*)&os[kr + p * 8][nc] =
            *(const float4*)&ob[(size_t)(k0 + kr + p * 8) * Nn + n_t + nc];
    }
    { // W2 tile 64c x 32k -> [k][c]
      int cc = t >> 2, k4 = (t & 3) * 4;
#pragma unroll
      for (int p = 0; p < 2; ++p) {
        int k = k4 + p * 16;
        float4 w4 = *(const float4*)&W2b[(size_t)cc * Mn + k0 + k];
        w2T[k + 0][cc] = w4.x; w2T[k + 1][cc] = w4.y;
        w2T[k + 2][cc] = w4.z; w2T[k + 3][cc] = w4.w;
      }
    }
    __syncthreads();
#pragma unroll
    for (int kk = 0; kk < 32; ++kk) {
      float4 w4 = *(const float4*)&w2T[kk][tc];
      float4 oa = *(const float4*)&os[kk][tn];
      float4 obb = *(const float4*)&os[kk][tn + 64];
      float w[4] = {w4.x, w4.y, w4.z, w4.w};
      float oo[8] = {oa.x, oa.y, oa.z, oa.w, obb.x, obb.y, obb.z, obb.w};
#pragma unroll
      for (int i = 0; i < 4; ++i)
#pragma unroll
        for (int jj = 0; jj < 8; ++jj) acc[i][jj] = fmaf(w[i], oo[jj], acc[i][jj]);
    }
    __syncthreads();
  }
  float g = gamma[0];
#pragma unroll
  for (int i = 0; i < 4; ++i) {
    int c = c_t + tc + i;
    float bias = b_c[c];
    size_t base = ((size_t)(b * Cn + c)) * Nn + n_t + tn;
#pragma unroll
    for (int h = 0; h < 2; ++h) {
      size_t idx = base + h * 64;
      float4 x4 = *(const float4*)&x[idx];
      float4 r;
      r.x = g * fmaxf(acc[i][h * 4 + 0] + bias, 0.f) + x4.x;
      r.y = g * fmaxf(acc[i][h * 4 + 1] + bias, 0.f) + x4.y;
      r.z = g * fmaxf(acc[i][h * 4 + 2] + bias, 0.f) + x4.z;
      r.w = g * fmaxf(acc[i][h * 4 + 3] + bias, 0.f) + x4.w;
      *(float4*)&out[idx] = r;
    }
  }
}

// ---------------------------------------------------------------------------
extern "C" void kernel_launch(void* const* d_in, const int* in_sizes, int n_in,
                              void* d_out, int out_size, void* d_ws, size_t ws_size,
                              hipStream_t stream) {
  const float* x   = (const float*)d_in[0];
  const float* w_o = (const float*)d_in[1];
  const float* b_o = (const float*)d_in[2];
  const float* w_v = (const float*)d_in[3];
  const float* b_v = (const float*)d_in[4];
  const float* w_c = (const float*)d_in[5];
  const float* b_c = (const float*)d_in[6];
  const float* gm  = (const float*)d_in[7];

  float* ws = (float*)d_ws;
  float* o  = ws;                               // B*M*N
  float* v  = o  + (size_t)Bn * Mn * Nn;        // B*M*N
  float* rm = v  + (size_t)Bn * Mn * Nn;        // B*M
  float* rs = rm + Bn * Mn;                     // B*M
  float* cm = rs + Bn * Mn;                     // B*N
  float* cs = cm + Bn * Nn;                     // B*N
  float* A  = cs + Bn * Nn;                     // B*M*M
  float* W2 = A  + (size_t)Bn * Mn * Mn;        // B*C*M
  float* Ap = W2 + (size_t)Bn * Cn * Mn;        // S*B*M*M partials

  // choose slice count S by available scratch (all choices are deterministic
  // across calls since ws_size is fixed)
  size_t base_floats = (size_t)(Ap - ws);
  int S = 32;
  if (ws_size < (base_floats + (size_t)32 * Bn * Mn * Mn) * sizeof(float)) S = 16;
  if (ws_size < (base_floats + (size_t)16 * Bn * Mn * Mn) * sizeof(float)) S = 8;
  const int ncols = Nn / S;

  k_proj<<<dim3(Nn / 32, Bn), 256, 0, stream>>>(x, w_o, b_o, w_v, b_v, o, v);
  k_rowstats<<<dim3(Bn * Mn), 256, 0, stream>>>(v, rm, rs);
  k_colstats<<<dim3(Bn * Nn / 256), 256, 0, stream>>>(v, cm, cs);
  k_accA<<<dim3(S, Bn), 256, 0, stream>>>(v, rm, rs, cm, cs, Ap, ncols);
  k_reduceA<<<dim3(Bn * Mn * Mn / 1024), 256, 0, stream>>>(Ap, A, S);
  k_w2<<<dim3(Mn / 64, Cn / 64, Bn), 256, 0, stream>>>(w_c, A, W2);
  k_final<<<dim3(Nn / 128, Cn / 64, Bn), 256, 0, stream>>>(W2, o, x, b_c, gm, (float*)d_out);
}

// Round 4
// 302.538 us; speedup vs baseline: 1.9300x; 1.2385x over previous
//
#include <hip/hip_runtime.h>
#include <math.h>

// Problem constants (fixed by the reference)
constexpr int Bn = 16;    // batch
constexpr int Cn = 256;   // in channels
constexpr int Mn = 128;   // med channels
constexpr int Nn = 4096;  // H*W

typedef short bf16x8 __attribute__((ext_vector_type(8)));     // 8 bf16 (4 VGPRs)
typedef float f32x4 __attribute__((ext_vector_type(4)));      // MFMA accum
typedef unsigned short us8 __attribute__((ext_vector_type(8)));
typedef unsigned short us4 __attribute__((ext_vector_type(4)));

static __device__ __forceinline__ unsigned short f2bf(float f) {
  union { float f; unsigned int u; } c{f};
  unsigned int u = c.u;
  u += 0x7FFFu + ((u >> 16) & 1u);   // RNE
  return (unsigned short)(u >> 16);
}

// ---------------------------------------------------------------------------
// P1: Wst[256][256] bf16 = stack(w_o, w_v) (k-contiguous rows)
// ---------------------------------------------------------------------------
__global__ __launch_bounds__(256) void k_prep_w(
    const float* __restrict__ w_o, const float* __restrict__ w_v,
    unsigned short* __restrict__ Wst) {
  int idx = blockIdx.x * 256 + threadIdx.x;       // over 256*256/4
  int row = idx >> 6;
  int c4 = (idx & 63) * 4;
  const float* src = (row < Mn) ? &w_o[(size_t)row * Cn + c4]
                                : &w_v[(size_t)(row - Mn) * Cn + c4];
  float4 f = *(const float4*)src;
  us4 g = {f2bf(f.x), f2bf(f.y), f2bf(f.z), f2bf(f.w)};
  *(us4*)&Wst[(size_t)row * Cn + c4] = g;
}

// ---------------------------------------------------------------------------
// P2: xT[b][n][c] bf16 = transpose+cast of x[b][c][n]. Both sides coalesced:
// reads are float4 along n (256B segments/instr), writes 16B granules along c
// (contiguous across lane groups). Tile: 64n x 128c per block, 2 c-halves.
// ---------------------------------------------------------------------------
__global__ __launch_bounds__(256) void k_prep_x(
    const float* __restrict__ x, unsigned short* __restrict__ xT) {
  const int b = blockIdx.z;
  const int c0 = blockIdx.y * 128;
  const int n0 = blockIdx.x * 64;
  const int t = threadIdx.x;
  const int n4 = (t & 15) * 4;          // 0..60
  const int c8 = c0 + (t >> 4) * 8;     // 8 consecutive c per thread
  const float* xb = x + ((size_t)b * Cn + c8) * Nn + n0 + n4;
  float4 r[8];
#pragma unroll
  for (int i = 0; i < 8; ++i) r[i] = *(const float4*)&xb[(size_t)i * Nn];
  unsigned short* dst = xT + ((size_t)b * Nn + n0 + n4) * Cn + c8;
#pragma unroll
  for (int j = 0; j < 4; ++j) {
    us8 g;
#pragma unroll
    for (int i = 0; i < 8; ++i) g[i] = f2bf(((const float*)&r[i])[j]);
    *(us8*)&dst[(size_t)j * Cn] = g;
  }
}

// ---------------------------------------------------------------------------
// K1 (MFMA): [o;v][b] = Wst @ x[b] + bias. Per batch: [256x256]@[256x4096].
// Block tile 128m x 128n, BK=64, K=256. LDS granule-major [g][row] so both
// staging writes and fragment reads are stride-1 16B ops (no conflicts).
// Wave w: 64x64 quadrant, 4x4 grid of 16x16x32 MFMAs.
// mt=0 -> o rows (bias b_o), mt=1 -> v rows (bias b_v).
// ---------------------------------------------------------------------------
__global__ __launch_bounds__(256) void k_proj_mfma(
    const unsigned short* __restrict__ Wst,
    const unsigned short* __restrict__ xT,
    const float* __restrict__ b_o, const float* __restrict__ b_v,
    float* __restrict__ o, float* __restrict__ v) {
  __shared__ unsigned short ldsA[8 * 128 * 8];  // [g(8)][m(128)] x 8 bf16
  __shared__ unsigned short ldsB[8 * 128 * 8];  // [g(8)][n(128)] x 8 bf16
  const int b = blockIdx.z;
  const int mt = blockIdx.y;
  const int nt = blockIdx.x;
  const int t = threadIdx.x;
  const int wave = t >> 6, lane = t & 63;
  const int quad = lane >> 4, l16 = lane & 15;
  const int wm = (wave & 1) * 64, wn = (wave >> 1) * 64;
  f32x4 acc[4][4] = {};
  const unsigned short* Wb = Wst + (size_t)mt * 128 * Cn;
  const unsigned short* xb = xT + ((size_t)b * Nn + nt * 128) * Cn;

  for (int k0 = 0; k0 < Cn; k0 += 64) {
#pragma unroll
    for (int p = 0; p < 4; ++p) {       // 1024 granules per tile, 4/thread
      int s = p * 256 + t;
      int g = s >> 7, row = s & 127;
      *(uint4*)&ldsA[(size_t)s * 8] = *(const uint4*)&Wb[(size_t)row * Cn + k0 + g * 8];
      *(uint4*)&ldsB[(size_t)s * 8] = *(const uint4*)&xb[(size_t)row * Cn + k0 + g * 8];
    }
    __syncthreads();
#pragma unroll
    for (int s = 0; s < 2; ++s) {       // two k-steps of 32
      bf16x8 af[4], bfr[4];
#pragma unroll
      for (int i = 0; i < 4; ++i)
        af[i] = *(const bf16x8*)&ldsA[(size_t)((s * 4 + quad) * 128 + wm + i * 16 + l16) * 8];
#pragma unroll
      for (int j = 0; j < 4; ++j)
        bfr[j] = *(const bf16x8*)&ldsB[(size_t)((s * 4 + quad) * 128 + wn + j * 16 + l16) * 8];
#pragma unroll
      for (int i = 0; i < 4; ++i)
#pragma unroll
        for (int j = 0; j < 4; ++j)
          acc[i][j] = __builtin_amdgcn_mfma_f32_16x16x32_bf16(af[i], bfr[j], acc[i][j], 0, 0, 0);
    }
    __syncthreads();
  }
  const float* bias = (mt == 0) ? b_o : b_v;
  float* dst = ((mt == 0) ? o : v) + (size_t)b * Mn * Nn + nt * 128;
#pragma unroll
  for (int i = 0; i < 4; ++i) {
#pragma unroll
    for (int r = 0; r < 4; ++r) {
      int m = wm + i * 16 + quad * 4 + r;
      float bi = bias[m];
#pragma unroll
      for (int j = 0; j < 4; ++j) {
        int n = wn + j * 16 + l16;
        dst[(size_t)m * Nn + n] = acc[i][j][r] + bi;
      }
    }
  }
}

// ---------------------------------------------------------------------------
// K2: row softmax stats over N for each (b,m): rm = max, rs = sum exp(v-rm)
// ---------------------------------------------------------------------------
__global__ __launch_bounds__(256) void k_rowstats(
    const float* __restrict__ v, float* __restrict__ rm, float* __restrict__ rs) {
  const int row = blockIdx.x;  // b*M + m
  const float* vr = v + (size_t)row * Nn;
  const int t = threadIdx.x;
  float vals[16];
  float mx = -1e30f;
#pragma unroll
  for (int p = 0; p < 4; ++p) {
    float4 v4 = *(const float4*)&vr[p * 1024 + t * 4];
    vals[p * 4 + 0] = v4.x; vals[p * 4 + 1] = v4.y;
    vals[p * 4 + 2] = v4.z; vals[p * 4 + 3] = v4.w;
    mx = fmaxf(mx, fmaxf(fmaxf(v4.x, v4.y), fmaxf(v4.z, v4.w)));
  }
  __shared__ float red[256];
  red[t] = mx;
  __syncthreads();
  for (int s = 128; s > 0; s >>= 1) {
    if (t < s) red[t] = fmaxf(red[t], red[t + s]);
    __syncthreads();
  }
  mx = red[0];
  __syncthreads();
  float sum = 0.f;
#pragma unroll
  for (int i = 0; i < 16; ++i) sum += __expf(vals[i] - mx);
  red[t] = sum;
  __syncthreads();
  for (int s = 128; s > 0; s >>= 1) {
    if (t < s) red[t] += red[t + s];
    __syncthreads();
  }
  if (t == 0) { rm[row] = mx; rs[row] = red[0]; }
}

// ---------------------------------------------------------------------------
// K3: column softmax stats over M for each (b,n): cm, cs
// ---------------------------------------------------------------------------
__global__ __launch_bounds__(256) void k_colstats(
    const float* __restrict__ v, float* __restrict__ cm, float* __restrict__ cs) {
  int idx = blockIdx.x * 256 + threadIdx.x;  // 0..B*N-1
  int b = idx >> 12;
  int n = idx & (Nn - 1);
  const float* vc = v + (size_t)b * Mn * Nn + n;
  float mx = -1e30f;
#pragma unroll 4
  for (int k = 0; k < Mn; ++k) mx = fmaxf(mx, vc[(size_t)k * Nn]);
  float sum = 0.f;
#pragma unroll 4
  for (int k = 0; k < Mn; ++k) sum += __expf(vc[(size_t)k * Nn] - mx);
  cm[idx] = mx;
  cs[idx] = sum;
}

// ---------------------------------------------------------------------------
// K4: partial A per n-slice (no atomics); k_reduceA sums the S partials.
// ---------------------------------------------------------------------------
__global__ __launch_bounds__(256) void k_accA(
    const float* __restrict__ v,
    const float* __restrict__ rm, const float* __restrict__ rs,
    const float* __restrict__ cm, const float* __restrict__ cs,
    float* __restrict__ Ap, int ncols) {
  __shared__ float vE[32][132];  // [n-in-chunk][m]  ev operand
  __shared__ float vS[32][132];  // [n-in-chunk][k]  es operand
  const int b = blockIdx.y;
  const int slice = blockIdx.x;
  const int nbase = slice * ncols;
  const int t = threadIdx.x;
  const int m0 = (t >> 4) * 8;   // 0..120
  const int k0 = (t & 15) * 8;   // 0..120
  const int rbase = t >> 3;      // 0..31
  const int c4 = (t & 7) * 4;    // 0..28
  float acc[8][8] = {};
  const float* vb = v + (size_t)b * Mn * Nn;

  float rmv[4], irs[4];
#pragma unroll
  for (int p = 0; p < 4; ++p) {
    int r = rbase + 32 * p;
    rmv[p] = rm[b * Mn + r];
    irs[p] = 1.0f / rs[b * Mn + r];
  }

  for (int ch = 0; ch < ncols; ch += 32) {
    const int n0c = nbase + ch;
    float4 cm4 = *(const float4*)&cm[b * Nn + n0c + c4];
    float4 cs4 = *(const float4*)&cs[b * Nn + n0c + c4];
    float cmv[4] = {cm4.x, cm4.y, cm4.z, cm4.w};
    float icv[4] = {1.0f / cs4.x, 1.0f / cs4.y, 1.0f / cs4.z, 1.0f / cs4.w};
#pragma unroll
    for (int p = 0; p < 4; ++p) {
      int r = rbase + 32 * p;
      float4 vv = *(const float4*)&vb[(size_t)r * Nn + n0c + c4];
      float a[4] = {vv.x, vv.y, vv.z, vv.w};
#pragma unroll
      for (int q = 0; q < 4; ++q) {
        vE[c4 + q][r] = __expf(a[q] - rmv[p]) * irs[p];
        vS[c4 + q][r] = __expf(a[q] - cmv[q]) * icv[q];
      }
    }
    __syncthreads();
#pragma unroll
    for (int jj = 0; jj < 32; ++jj) {
      float4 e0 = *(const float4*)&vE[jj][m0];
      float4 e1 = *(const float4*)&vE[jj][m0 + 4];
      float4 s0 = *(const float4*)&vS[jj][k0];
      float4 s1 = *(const float4*)&vS[jj][k0 + 4];
      float e[8] = {e0.x, e0.y, e0.z, e0.w, e1.x, e1.y, e1.z, e1.w};
      float s[8] = {s0.x, s0.y, s0.z, s0.w, s1.x, s1.y, s1.z, s1.w};
#pragma unroll
      for (int i = 0; i < 8; ++i)
#pragma unroll
        for (int j = 0; j < 8; ++j) acc[i][j] = fmaf(e[i], s[j], acc[i][j]);
    }
    __syncthreads();
  }
  float* Apb = Ap + ((size_t)slice * Bn + b) * (Mn * Mn);
#pragma unroll
  for (int i = 0; i < 8; ++i) {
#pragma unroll
    for (int j = 0; j < 8; j += 4) {
      float4 r4 = {acc[i][j], acc[i][j + 1], acc[i][j + 2], acc[i][j + 3]};
      *(float4*)&Apb[(size_t)(m0 + i) * Mn + k0 + j] = r4;
    }
  }
}

// ---------------------------------------------------------------------------
// K4b: A[b][idx] = sum_s Ap[s][b][idx]
// ---------------------------------------------------------------------------
__global__ __launch_bounds__(256) void k_reduceA(
    const float* __restrict__ Ap, float* __restrict__ A, int S) {
  int tid = blockIdx.x * 256 + threadIdx.x;           // over Bn*Mn*Mn/4
  int idx4 = tid * 4;
  int b = idx4 / (Mn * Mn);
  int off = idx4 - b * (Mn * Mn);
  float4 s = {0.f, 0.f, 0.f, 0.f};
  for (int s0 = 0; s0 < S; ++s0) {
    float4 p = *(const float4*)&Ap[((size_t)s0 * Bn + b) * (Mn * Mn) + off];
    s.x += p.x; s.y += p.y; s.z += p.z; s.w += p.w;
  }
  *(float4*)&A[idx4] = s;
}

// ---------------------------------------------------------------------------
// K5: W2[b,c,m] = sum_k w_c[c,k] * A[b,m,k]
// ---------------------------------------------------------------------------
__global__ __launch_bounds__(256) void k_w2(
    const float* __restrict__ w_c, const float* __restrict__ A, float* __restrict__ W2) {
  __shared__ float As[64][68];   // [k][m-local]
  __shared__ float wcs[64][68];  // [k][c-local]
  const int b = blockIdx.z;
  const int m0 = blockIdx.x * 64;
  const int c0 = blockIdx.y * 64;
  const int t = threadIdx.x;
  const int tc = (t >> 4) * 4, tmm = (t & 15) * 4;
  float acc[4][4] = {};
  for (int k0 = 0; k0 < Mn; k0 += 64) {
    int r = t >> 2;             // 0..63
    int k4 = (t & 3) * 4;
#pragma unroll
    for (int p = 0; p < 4; ++p) {
      int k = k4 + p * 16;
      float4 a4 = *(const float4*)&A[((size_t)(b * Mn + m0 + r)) * Mn + k0 + k];
      As[k + 0][r] = a4.x; As[k + 1][r] = a4.y; As[k + 2][r] = a4.z; As[k + 3][r] = a4.w;
      float4 w4 = *(const float4*)&w_c[(size_t)(c0 + r) * Mn + k0 + k];
      wcs[k + 0][r] = w4.x; wcs[k + 1][r] = w4.y; wcs[k + 2][r] = w4.z; wcs[k + 3][r] = w4.w;
    }
    __syncthreads();
#pragma unroll
    for (int kk = 0; kk < 64; ++kk) {
      float4 w4 = *(const float4*)&wcs[kk][tc];
      float4 a4 = *(const float4*)&As[kk][tmm];
      float w[4] = {w4.x, w4.y, w4.z, w4.w};
      float a[4] = {a4.x, a4.y, a4.z, a4.w};
#pragma unroll
      for (int i = 0; i < 4; ++i)
#pragma unroll
        for (int jj = 0; jj < 4; ++jj) acc[i][jj] = fmaf(w[i], a[jj], acc[i][jj]);
    }
    __syncthreads();
  }
#pragma unroll
  for (int i = 0; i < 4; ++i) {
    size_t base = ((size_t)(b * Cn + c0 + tc + i)) * Mn + m0 + tmm;
    float4 r4 = {acc[i][0], acc[i][1], acc[i][2], acc[i][3]};
    *(float4*)&W2[base] = r4;
  }
}

// ---------------------------------------------------------------------------
// K6: out[b,c,n] = gamma*relu(sum_m W2[b,c,m]*o[b,m,n] + b_c[c]) + x[b,c,n]
// ---------------------------------------------------------------------------
__global__ __launch_bounds__(256) void k_final(
    const float* __restrict__ W2, const float* __restrict__ o,
    const float* __restrict__ x, const float* __restrict__ b_c,
    const float* __restrict__ gamma, float* __restrict__ out) {
  __shared__ float os[32][128];  // [k][n]
  __shared__ float w2T[32][68];  // [k][c-local]
  const int b = blockIdx.z;
  const int c_t = blockIdx.y * 64;
  const int n_t = blockIdx.x * 128;
  const int t = threadIdx.x;
  const int tc = (t >> 4) * 4;       // 0..60
  const int tn = (t & 15) * 4;       // 0..60 (+64 for second half)
  float acc[4][8] = {};
  const float* ob = o + (size_t)b * Mn * Nn;
  const float* W2b = W2 + ((size_t)b * Cn + c_t) * Mn;

  for (int k0 = 0; k0 < Mn; k0 += 32) {
    { // o tile 32k x 128n
      int kr = t >> 5, nc = (t & 31) * 4;
#pragma unroll
      for (int p = 0; p < 4; ++p)
        *(float4*)&os[kr + p * 8][nc] =
            *(const float4*)&ob[(size_t)(k0 + kr + p * 8) * Nn + n_t + nc];
    }
    { // W2 tile 64c x 32k -> [k][c]
      int cc = t >> 2, k4 = (t & 3) * 4;
#pragma unroll
      for (int p = 0; p < 2; ++p) {
        int k = k4 + p * 16;
        float4 w4 = *(const float4*)&W2b[(size_t)cc * Mn + k0 + k];
        w2T[k + 0][cc] = w4.x; w2T[k + 1][cc] = w4.y;
        w2T[k + 2][cc] = w4.z; w2T[k + 3][cc] = w4.w;
      }
    }
    __syncthreads();
#pragma unroll
    for (int kk = 0; kk < 32; ++kk) {
      float4 w4 = *(const float4*)&w2T[kk][tc];
      float4 oa = *(const float4*)&os[kk][tn];
      float4 obb = *(const float4*)&os[kk][tn + 64];
      float w[4] = {w4.x, w4.y, w4.z, w4.w};
      float oo[8] = {oa.x, oa.y, oa.z, oa.w, obb.x, obb.y, obb.z, obb.w};
#pragma unroll
      for (int i = 0; i < 4; ++i)
#pragma unroll
        for (int jj = 0; jj < 8; ++jj) acc[i][jj] = fmaf(w[i], oo[jj], acc[i][jj]);
    }
    __syncthreads();
  }
  float g = gamma[0];
#pragma unroll
  for (int i = 0; i < 4; ++i) {
    int c = c_t + tc + i;
    float bias = b_c[c];
    size_t base = ((size_t)(b * Cn + c)) * Nn + n_t + tn;
#pragma unroll
    for (int h = 0; h < 2; ++h) {
      size_t idx = base + h * 64;
      float4 x4 = *(const float4*)&x[idx];
      float4 r;
      r.x = g * fmaxf(acc[i][h * 4 + 0] + bias, 0.f) + x4.x;
      r.y = g * fmaxf(acc[i][h * 4 + 1] + bias, 0.f) + x4.y;
      r.z = g * fmaxf(acc[i][h * 4 + 2] + bias, 0.f) + x4.z;
      r.w = g * fmaxf(acc[i][h * 4 + 3] + bias, 0.f) + x4.w;
      *(float4*)&out[idx] = r;
    }
  }
}

// ---------------------------------------------------------------------------
extern "C" void kernel_launch(void* const* d_in, const int* in_sizes, int n_in,
                              void* d_out, int out_size, void* d_ws, size_t ws_size,
                              hipStream_t stream) {
  const float* x   = (const float*)d_in[0];
  const float* w_o = (const float*)d_in[1];
  const float* b_o = (const float*)d_in[2];
  const float* w_v = (const float*)d_in[3];
  const float* b_v = (const float*)d_in[4];
  const float* w_c = (const float*)d_in[5];
  const float* b_c = (const float*)d_in[6];
  const float* gm  = (const float*)d_in[7];

  float* ws = (float*)d_ws;
  float* o  = ws;                               // B*M*N
  float* v  = o  + (size_t)Bn * Mn * Nn;        // B*M*N
  float* rm = v  + (size_t)Bn * Mn * Nn;        // B*M
  float* rs = rm + Bn * Mn;                     // B*M
  float* cm = rs + Bn * Mn;                     // B*N
  float* cs = cm + Bn * Nn;                     // B*N
  float* A  = cs + Bn * Nn;                     // B*M*M
  float* W2 = A  + (size_t)Bn * Mn * Mn;        // B*C*M
  unsigned short* xT  = (unsigned short*)(W2 + (size_t)Bn * Cn * Mn);  // B*N*C bf16
  unsigned short* Wst = xT + (size_t)Bn * Nn * Cn;                     // 256*256 bf16
  float* Ap = (float*)(Wst + (size_t)Cn * Cn);  // S*B*M*M partials (16B-aligned)

  size_t base_floats = (size_t)(Ap - ws);
  int S = 32;
  if (ws_size < (base_floats + (size_t)32 * Bn * Mn * Mn) * sizeof(float)) S = 16;
  if (ws_size < (base_floats + (size_t)16 * Bn * Mn * Mn) * sizeof(float)) S = 8;
  const int ncols = Nn / S;

  k_prep_w<<<dim3(Cn * Cn / 1024), 256, 0, stream>>>(w_o, w_v, Wst);
  k_prep_x<<<dim3(Nn / 64, 2, Bn), 256, 0, stream>>>(x, xT);
  k_proj_mfma<<<dim3(Nn / 128, 2, Bn), 256, 0, stream>>>(Wst, xT, b_o, b_v, o, v);
  k_rowstats<<<dim3(Bn * Mn), 256, 0, stream>>>(v, rm, rs);
  k_colstats<<<dim3(Bn * Nn / 256), 256, 0, stream>>>(v, cm, cs);
  k_accA<<<dim3(S, Bn), 256, 0, stream>>>(v, rm, rs, cm, cs, Ap, ncols);
  k_reduceA<<<dim3(Bn * Mn * Mn / 1024), 256, 0, stream>>>(Ap, A, S);
  k_w2<<<dim3(Mn / 64, Cn / 64, Bn), 256, 0, stream>>>(w_c, A, W2);
  k_final<<<dim3(Nn / 128, Cn / 64, Bn), 256, 0, stream>>>(W2, o, x, b_c, gm, (float*)d_out);
}

// Round 5
// 273.037 us; speedup vs baseline: 2.1385x; 1.1080x over previous
//
#include <hip/hip_runtime.h>
#include <math.h>

// Problem constants (fixed by the reference)
constexpr int Bn = 16;    // batch
constexpr int Cn = 256;   // in channels
constexpr int Mn = 128;   // med channels
constexpr int Nn = 4096;  // H*W

typedef short bf16x8 __attribute__((ext_vector_type(8)));     // 8 bf16 (4 VGPRs)
typedef float f32x4 __attribute__((ext_vector_type(4)));      // MFMA accum
typedef unsigned short us8 __attribute__((ext_vector_type(8)));
typedef unsigned short us4 __attribute__((ext_vector_type(4)));

static __device__ __forceinline__ unsigned short f2bf(float f) {
  union { float f; unsigned int u; } c{f};
  unsigned int u = c.u;
  u += 0x7FFFu + ((u >> 16) & 1u);   // RNE
  return (unsigned short)(u >> 16);
}

// ---------------------------------------------------------------------------
// P1: Wst[256][256] bf16 = stack(w_o, w_v) (k-contiguous rows)
// ---------------------------------------------------------------------------
__global__ __launch_bounds__(256) void k_prep_w(
    const float* __restrict__ w_o, const float* __restrict__ w_v,
    unsigned short* __restrict__ Wst) {
  int idx = blockIdx.x * 256 + threadIdx.x;       // over 256*256/4
  int row = idx >> 6;
  int c4 = (idx & 63) * 4;
  const float* src = (row < Mn) ? &w_o[(size_t)row * Cn + c4]
                                : &w_v[(size_t)(row - Mn) * Cn + c4];
  float4 f = *(const float4*)src;
  us4 g = {f2bf(f.x), f2bf(f.y), f2bf(f.z), f2bf(f.w)};
  *(us4*)&Wst[(size_t)row * Cn + c4] = g;
}

// ---------------------------------------------------------------------------
// P2: xT[b][n][c] bf16 = transpose+cast of x[b][c][n].
// ---------------------------------------------------------------------------
__global__ __launch_bounds__(256) void k_prep_x(
    const float* __restrict__ x, unsigned short* __restrict__ xT) {
  const int b = blockIdx.z;
  const int c0 = blockIdx.y * 128;
  const int n0 = blockIdx.x * 64;
  const int t = threadIdx.x;
  const int n4 = (t & 15) * 4;          // 0..60
  const int c8 = c0 + (t >> 4) * 8;     // 8 consecutive c per thread
  const float* xb = x + ((size_t)b * Cn + c8) * Nn + n0 + n4;
  float4 r[8];
#pragma unroll
  for (int i = 0; i < 8; ++i) r[i] = *(const float4*)&xb[(size_t)i * Nn];
  unsigned short* dst = xT + ((size_t)b * Nn + n0 + n4) * Cn + c8;
#pragma unroll
  for (int j = 0; j < 4; ++j) {
    us8 g;
#pragma unroll
    for (int i = 0; i < 8; ++i) g[i] = f2bf(((const float*)&r[i])[j]);
    *(us8*)&dst[(size_t)j * Cn] = g;
  }
}

// ---------------------------------------------------------------------------
// K1 (MFMA): per batch [256x256]@[256x4096] for o and v.
// mt=1 -> v rows: D[m][n] fp32 to v (stats/accA consume this layout).
// mt=0 -> o rows: operand-swapped mfma gives D[n][m] = o^T; written bf16 to
//         oT[b][n][m] (m-contiguous) — the exact B-operand layout k_final
//         needs, at 1/4 the write traffic of fp32 o[m][n].
// ---------------------------------------------------------------------------
__global__ __launch_bounds__(256) void k_proj_mfma(
    const unsigned short* __restrict__ Wst,
    const unsigned short* __restrict__ xT,
    const float* __restrict__ b_o, const float* __restrict__ b_v,
    unsigned short* __restrict__ oT, float* __restrict__ v) {
  __shared__ unsigned short ldsA[8 * 128 * 8];  // [g(8)][row(128)] x 8 bf16
  __shared__ unsigned short ldsB[8 * 128 * 8];
  const int b = blockIdx.z;
  const int mt = blockIdx.y;
  const int nt = blockIdx.x;
  const int t = threadIdx.x;
  const int wave = t >> 6, lane = t & 63;
  const int quad = lane >> 4, l16 = lane & 15;
  const int wm = (wave & 1) * 64, wn = (wave >> 1) * 64;
  f32x4 acc[4][4] = {};
  const unsigned short* Wb = Wst + (size_t)mt * 128 * Cn;
  const unsigned short* xb = xT + ((size_t)b * Nn + nt * 128) * Cn;

  for (int k0 = 0; k0 < Cn; k0 += 64) {
#pragma unroll
    for (int p = 0; p < 4; ++p) {       // 1024 granules per tile, 4/thread
      int s = p * 256 + t;
      int g = s >> 7, row = s & 127;
      *(uint4*)&ldsA[(size_t)s * 8] = *(const uint4*)&Wb[(size_t)row * Cn + k0 + g * 8];
      *(uint4*)&ldsB[(size_t)s * 8] = *(const uint4*)&xb[(size_t)row * Cn + k0 + g * 8];
    }
    __syncthreads();
#pragma unroll
    for (int s = 0; s < 2; ++s) {       // two k-steps of 32
      bf16x8 af[4], bfr[4];
#pragma unroll
      for (int i = 0; i < 4; ++i)
        af[i] = *(const bf16x8*)&ldsA[(size_t)((s * 4 + quad) * 128 + wm + i * 16 + l16) * 8];
#pragma unroll
      for (int j = 0; j < 4; ++j)
        bfr[j] = *(const bf16x8*)&ldsB[(size_t)((s * 4 + quad) * 128 + wn + j * 16 + l16) * 8];
      if (mt) {
#pragma unroll
        for (int i = 0; i < 4; ++i)
#pragma unroll
          for (int j = 0; j < 4; ++j)
            acc[i][j] = __builtin_amdgcn_mfma_f32_16x16x32_bf16(af[i], bfr[j], acc[i][j], 0, 0, 0);
      } else {
        // swapped: D row entity = n (x side), col entity = m (W side)
#pragma unroll
        for (int i = 0; i < 4; ++i)
#pragma unroll
          for (int j = 0; j < 4; ++j)
            acc[i][j] = __builtin_amdgcn_mfma_f32_16x16x32_bf16(bfr[i], af[j], acc[i][j], 0, 0, 0);
      }
    }
    __syncthreads();
  }
  if (mt) {  // v: D[m][n] fp32
    float* dst = v + (size_t)b * Mn * Nn + nt * 128;
#pragma unroll
    for (int i = 0; i < 4; ++i) {
#pragma unroll
      for (int r = 0; r < 4; ++r) {
        int m = wm + i * 16 + quad * 4 + r;
        float bi = b_v[m];
#pragma unroll
        for (int j = 0; j < 4; ++j) {
          int n = wn + j * 16 + l16;
          dst[(size_t)m * Nn + n] = acc[i][j][r] + bi;
        }
      }
    }
  } else {   // o^T: D[n][m] -> bf16 oT[b][n][m]
    float bo_j[4];
#pragma unroll
    for (int j = 0; j < 4; ++j) bo_j[j] = b_o[wm + j * 16 + l16];
#pragma unroll
    for (int i = 0; i < 4; ++i) {
#pragma unroll
      for (int r = 0; r < 4; ++r) {
        int n = nt * 128 + wn + i * 16 + quad * 4 + r;
        unsigned short* row = &oT[((size_t)b * Nn + n) * Mn];
#pragma unroll
        for (int j = 0; j < 4; ++j)
          row[wm + j * 16 + l16] = f2bf(acc[i][j][r] + bo_j[j]);
      }
    }
  }
}

// ---------------------------------------------------------------------------
// K2: row softmax stats over N for each (b,m): rm = max, rs = sum exp(v-rm)
// ---------------------------------------------------------------------------
__global__ __launch_bounds__(256) void k_rowstats(
    const float* __restrict__ v, float* __restrict__ rm, float* __restrict__ rs) {
  const int row = blockIdx.x;  // b*M + m
  const float* vr = v + (size_t)row * Nn;
  const int t = threadIdx.x;
  float vals[16];
  float mx = -1e30f;
#pragma unroll
  for (int p = 0; p < 4; ++p) {
    float4 v4 = *(const float4*)&vr[p * 1024 + t * 4];
    vals[p * 4 + 0] = v4.x; vals[p * 4 + 1] = v4.y;
    vals[p * 4 + 2] = v4.z; vals[p * 4 + 3] = v4.w;
    mx = fmaxf(mx, fmaxf(fmaxf(v4.x, v4.y), fmaxf(v4.z, v4.w)));
  }
  __shared__ float red[256];
  red[t] = mx;
  __syncthreads();
  for (int s = 128; s > 0; s >>= 1) {
    if (t < s) red[t] = fmaxf(red[t], red[t + s]);
    __syncthreads();
  }
  mx = red[0];
  __syncthreads();
  float sum = 0.f;
#pragma unroll
  for (int i = 0; i < 16; ++i) sum += __expf(vals[i] - mx);
  red[t] = sum;
  __syncthreads();
  for (int s = 128; s > 0; s >>= 1) {
    if (t < s) red[t] += red[t + s];
    __syncthreads();
  }
  if (t == 0) { rm[row] = mx; rs[row] = red[0]; }
}

// ---------------------------------------------------------------------------
// K3: column softmax stats over M for each (b,n): cm, cs
// ---------------------------------------------------------------------------
__global__ __launch_bounds__(256) void k_colstats(
    const float* __restrict__ v, float* __restrict__ cm, float* __restrict__ cs) {
  int idx = blockIdx.x * 256 + threadIdx.x;  // 0..B*N-1
  int b = idx >> 12;
  int n = idx & (Nn - 1);
  const float* vc = v + (size_t)b * Mn * Nn + n;
  float mx = -1e30f;
#pragma unroll 4
  for (int k = 0; k < Mn; ++k) mx = fmaxf(mx, vc[(size_t)k * Nn]);
  float sum = 0.f;
#pragma unroll 4
  for (int k = 0; k < Mn; ++k) sum += __expf(vc[(size_t)k * Nn] - mx);
  cm[idx] = mx;
  cs[idx] = sum;
}

// ---------------------------------------------------------------------------
// K4: partial A per n-slice (no atomics); k_reduceA sums the S partials.
// ---------------------------------------------------------------------------
__global__ __launch_bounds__(256) void k_accA(
    const float* __restrict__ v,
    const float* __restrict__ rm, const float* __restrict__ rs,
    const float* __restrict__ cm, const float* __restrict__ cs,
    float* __restrict__ Ap, int ncols) {
  __shared__ float vE[32][132];  // [n-in-chunk][m]  ev operand
  __shared__ float vS[32][132];  // [n-in-chunk][k]  es operand
  const int b = blockIdx.y;
  const int slice = blockIdx.x;
  const int nbase = slice * ncols;
  const int t = threadIdx.x;
  const int m0 = (t >> 4) * 8;   // 0..120
  const int k0 = (t & 15) * 8;   // 0..120
  const int rbase = t >> 3;      // 0..31
  const int c4 = (t & 7) * 4;    // 0..28
  float acc[8][8] = {};
  const float* vb = v + (size_t)b * Mn * Nn;

  float rmv[4], irs[4];
#pragma unroll
  for (int p = 0; p < 4; ++p) {
    int r = rbase + 32 * p;
    rmv[p] = rm[b * Mn + r];
    irs[p] = 1.0f / rs[b * Mn + r];
  }

  for (int ch = 0; ch < ncols; ch += 32) {
    const int n0c = nbase + ch;
    float4 cm4 = *(const float4*)&cm[b * Nn + n0c + c4];
    float4 cs4 = *(const float4*)&cs[b * Nn + n0c + c4];
    float cmv[4] = {cm4.x, cm4.y, cm4.z, cm4.w};
    float icv[4] = {1.0f / cs4.x, 1.0f / cs4.y, 1.0f / cs4.z, 1.0f / cs4.w};
#pragma unroll
    for (int p = 0; p < 4; ++p) {
      int r = rbase + 32 * p;
      float4 vv = *(const float4*)&vb[(size_t)r * Nn + n0c + c4];
      float a[4] = {vv.x, vv.y, vv.z, vv.w};
#pragma unroll
      for (int q = 0; q < 4; ++q) {
        vE[c4 + q][r] = __expf(a[q] - rmv[p]) * irs[p];
        vS[c4 + q][r] = __expf(a[q] - cmv[q]) * icv[q];
      }
    }
    __syncthreads();
#pragma unroll
    for (int jj = 0; jj < 32; ++jj) {
      float4 e0 = *(const float4*)&vE[jj][m0];
      float4 e1 = *(const float4*)&vE[jj][m0 + 4];
      float4 s0 = *(const float4*)&vS[jj][k0];
      float4 s1 = *(const float4*)&vS[jj][k0 + 4];
      float e[8] = {e0.x, e0.y, e0.z, e0.w, e1.x, e1.y, e1.z, e1.w};
      float s[8] = {s0.x, s0.y, s0.z, s0.w, s1.x, s1.y, s1.z, s1.w};
#pragma unroll
      for (int i = 0; i < 8; ++i)
#pragma unroll
        for (int j = 0; j < 8; ++j) acc[i][j] = fmaf(e[i], s[j], acc[i][j]);
    }
    __syncthreads();
  }
  float* Apb = Ap + ((size_t)slice * Bn + b) * (Mn * Mn);
#pragma unroll
  for (int i = 0; i < 8; ++i) {
#pragma unroll
    for (int j = 0; j < 8; j += 4) {
      float4 r4 = {acc[i][j], acc[i][j + 1], acc[i][j + 2], acc[i][j + 3]};
      *(float4*)&Apb[(size_t)(m0 + i) * Mn + k0 + j] = r4;
    }
  }
}

// ---------------------------------------------------------------------------
// K4b: A[b][idx] = sum_s Ap[s][b][idx]
// ---------------------------------------------------------------------------
__global__ __launch_bounds__(256) void k_reduceA(
    const float* __restrict__ Ap, float* __restrict__ A, int S) {
  int tid = blockIdx.x * 256 + threadIdx.x;           // over Bn*Mn*Mn/4
  int idx4 = tid * 4;
  int b = idx4 / (Mn * Mn);
  int off = idx4 - b * (Mn * Mn);
  float4 s = {0.f, 0.f, 0.f, 0.f};
  for (int s0 = 0; s0 < S; ++s0) {
    float4 p = *(const float4*)&Ap[((size_t)s0 * Bn + b) * (Mn * Mn) + off];
    s.x += p.x; s.y += p.y; s.z += p.z; s.w += p.w;
  }
  *(float4*)&A[idx4] = s;
}

// ---------------------------------------------------------------------------
// K5: W2bf[b,c,m] = bf16( sum_k w_c[c,k] * A[b,m,k] )  (m-contiguous = the
// A-operand K-layout k_final needs)
// ---------------------------------------------------------------------------
__global__ __launch_bounds__(256) void k_w2(
    const float* __restrict__ w_c, const float* __restrict__ A,
    unsigned short* __restrict__ W2bf) {
  __shared__ float As[64][68];   // [k][m-local]
  __shared__ float wcs[64][68];  // [k][c-local]
  const int b = blockIdx.z;
  const int m0 = blockIdx.x * 64;
  const int c0 = blockIdx.y * 64;
  const int t = threadIdx.x;
  const int tc = (t >> 4) * 4, tmm = (t & 15) * 4;
  float acc[4][4] = {};
  for (int k0 = 0; k0 < Mn; k0 += 64) {
    int r = t >> 2;             // 0..63
    int k4 = (t & 3) * 4;
#pragma unroll
    for (int p = 0; p < 4; ++p) {
      int k = k4 + p * 16;
      float4 a4 = *(const float4*)&A[((size_t)(b * Mn + m0 + r)) * Mn + k0 + k];
      As[k + 0][r] = a4.x; As[k + 1][r] = a4.y; As[k + 2][r] = a4.z; As[k + 3][r] = a4.w;
      float4 w4 = *(const float4*)&w_c[(size_t)(c0 + r) * Mn + k0 + k];
      wcs[k + 0][r] = w4.x; wcs[k + 1][r] = w4.y; wcs[k + 2][r] = w4.z; wcs[k + 3][r] = w4.w;
    }
    __syncthreads();
#pragma unroll
    for (int kk = 0; kk < 64; ++kk) {
      float4 w4 = *(const float4*)&wcs[kk][tc];
      float4 a4 = *(const float4*)&As[kk][tmm];
      float w[4] = {w4.x, w4.y, w4.z, w4.w};
      float a[4] = {a4.x, a4.y, a4.z, a4.w};
#pragma unroll
      for (int i = 0; i < 4; ++i)
#pragma unroll
        for (int jj = 0; jj < 4; ++jj) acc[i][jj] = fmaf(w[i], a[jj], acc[i][jj]);
    }
    __syncthreads();
  }
#pragma unroll
  for (int i = 0; i < 4; ++i) {
    us4 g4 = {f2bf(acc[i][0]), f2bf(acc[i][1]), f2bf(acc[i][2]), f2bf(acc[i][3])};
    *(us4*)&W2bf[((size_t)(b * Cn + c0 + tc + i)) * Mn + m0 + tmm] = g4;
  }
}

// ---------------------------------------------------------------------------
// K6 (MFMA): out[b,c,n] = gamma*relu(sum_m W2bf[c,m]*oT[n,m] + b_c[c]) + x
// Tile 128c x 128n, K=128 fully staged. LDS slot = row*16 + (g ^ (row&15)):
// global reads 256B-coalesced, LDS writes conflict-free, reads 2-way (free).
// ---------------------------------------------------------------------------
__global__ __launch_bounds__(256) void k_final_mfma(
    const unsigned short* __restrict__ W2bf, const unsigned short* __restrict__ oT,
    const float* __restrict__ x, const float* __restrict__ b_c,
    const float* __restrict__ gamma, float* __restrict__ out) {
  __shared__ us8 ldsA[128 * 16];  // 32 KB: [c-row][granule-swizzled]
  __shared__ us8 ldsB[128 * 16];  // 32 KB: [n-row][granule-swizzled]
  const int b = blockIdx.z;
  const int c_t = blockIdx.y * 128;
  const int n_t = blockIdx.x * 128;
  const int t = threadIdx.x;
  const int wave = t >> 6, lane = t & 63;
  const int quad = lane >> 4, l16 = lane & 15;
  const int wc = (wave & 1) * 64, wn = (wave >> 1) * 64;
  const unsigned short* W2b = W2bf + ((size_t)b * Cn + c_t) * Mn;
  const unsigned short* oTb = oT + ((size_t)b * Nn + n_t) * Mn;

#pragma unroll
  for (int p = 0; p < 8; ++p) {   // 2048 granules per operand, 8/thread
    int s = p * 256 + t;
    int row = s >> 4, g = s & 15;
    int slot = row * 16 + (g ^ (row & 15));
    ldsA[slot] = *(const us8*)&W2b[(size_t)row * Mn + g * 8];
    ldsB[slot] = *(const us8*)&oTb[(size_t)row * Mn + g * 8];
  }
  __syncthreads();

  f32x4 acc[4][4] = {};
#pragma unroll
  for (int s = 0; s < 4; ++s) {
    int gq = s * 4 + quad;
    int xo = gq ^ l16;
    bf16x8 af[4], bfr[4];
#pragma unroll
    for (int i = 0; i < 4; ++i)
      af[i] = *(const bf16x8*)&ldsA[(wc + i * 16 + l16) * 16 + xo];
#pragma unroll
    for (int j = 0; j < 4; ++j)
      bfr[j] = *(const bf16x8*)&ldsB[(wn + j * 16 + l16) * 16 + xo];
#pragma unroll
    for (int i = 0; i < 4; ++i)
#pragma unroll
      for (int j = 0; j < 4; ++j)
        acc[i][j] = __builtin_amdgcn_mfma_f32_16x16x32_bf16(af[i], bfr[j], acc[i][j], 0, 0, 0);
  }

  float g = gamma[0];
#pragma unroll
  for (int i = 0; i < 4; ++i) {
#pragma unroll
    for (int r = 0; r < 4; ++r) {
      int c = c_t + wc + i * 16 + quad * 4 + r;
      float bias = b_c[c];
      const float* xr = &x[((size_t)b * Cn + c) * Nn + n_t];
      float* orow = &out[((size_t)b * Cn + c) * Nn + n_t];
#pragma unroll
      for (int j = 0; j < 4; ++j) {
        int n = wn + j * 16 + l16;
        orow[n] = g * fmaxf(acc[i][j][r] + bias, 0.f) + xr[n];
      }
    }
  }
}

// ---------------------------------------------------------------------------
extern "C" void kernel_launch(void* const* d_in, const int* in_sizes, int n_in,
                              void* d_out, int out_size, void* d_ws, size_t ws_size,
                              hipStream_t stream) {
  const float* x   = (const float*)d_in[0];
  const float* w_o = (const float*)d_in[1];
  const float* b_o = (const float*)d_in[2];
  const float* w_v = (const float*)d_in[3];
  const float* b_v = (const float*)d_in[4];
  const float* w_c = (const float*)d_in[5];
  const float* b_c = (const float*)d_in[6];
  const float* gm  = (const float*)d_in[7];

  float* ws = (float*)d_ws;
  float* v  = ws;                               // B*M*N fp32
  float* rm = v  + (size_t)Bn * Mn * Nn;        // B*M
  float* rs = rm + Bn * Mn;                     // B*M
  float* cm = rs + Bn * Mn;                     // B*N
  float* cs = cm + Bn * Nn;                     // B*N
  float* A  = cs + Bn * Nn;                     // B*M*M
  unsigned short* oT   = (unsigned short*)(A + (size_t)Bn * Mn * Mn); // B*N*M bf16
  unsigned short* W2bf = oT + (size_t)Bn * Nn * Mn;                   // B*C*M bf16
  unsigned short* xT   = W2bf + (size_t)Bn * Cn * Mn;                 // B*N*C bf16
  unsigned short* Wst  = xT + (size_t)Bn * Nn * Cn;                   // C*C bf16
  float* Ap = (float*)(Wst + (size_t)Cn * Cn);  // S*B*M*M partials

  size_t base_bytes = (size_t)((char*)Ap - (char*)ws);
  int S = 32;
  if (ws_size < base_bytes + (size_t)32 * Bn * Mn * Mn * sizeof(float)) S = 16;
  if (ws_size < base_bytes + (size_t)16 * Bn * Mn * Mn * sizeof(float)) S = 8;
  const int ncols = Nn / S;

  k_prep_w<<<dim3(Cn * Cn / 1024), 256, 0, stream>>>(w_o, w_v, Wst);
  k_prep_x<<<dim3(Nn / 64, 2, Bn), 256, 0, stream>>>(x, xT);
  k_proj_mfma<<<dim3(Nn / 128, 2, Bn), 256, 0, stream>>>(Wst, xT, b_o, b_v, oT, v);
  k_rowstats<<<dim3(Bn * Mn), 256, 0, stream>>>(v, rm, rs);
  k_colstats<<<dim3(Bn * Nn / 256), 256, 0, stream>>>(v, cm, cs);
  k_accA<<<dim3(S, Bn), 256, 0, stream>>>(v, rm, rs, cm, cs, Ap, ncols);
  k_reduceA<<<dim3(Bn * Mn * Mn / 1024), 256, 0, stream>>>(Ap, A, S);
  k_w2<<<dim3(Mn / 64, Cn / 64, Bn), 256, 0, stream>>>(w_c, A, W2bf);
  k_final_mfma<<<dim3(Nn / 128, Cn / 128, Bn), 256, 0, stream>>>(W2bf, oT, x, b_c, gm, (float*)d_out);
}